// Round 5
// baseline (891.194 us; speedup 1.0000x reference)
//
#include <hip/hip_runtime.h>
#include <hip/hip_bf16.h>

// ---------------------------------------------------------------------------
// 2-layer GCN:  out = GCNConv(GCNConv(x, W1), W2)  with shared edge_index.
//   deg[i]  = 1 + in-degree(i)            (self-loop folded in)
//   dis[i]  = rsqrt(deg[i])
//   layer:  out[i] = dis[i]^2 * h[i] + sum_{e: dst=i} dis[src]*dis[i]*h[src]
// ---------------------------------------------------------------------------

#define N_NODES 100000
#define F_IN 512
#define F_OUT 16

// ---- degree init: deg[i] = 1.0 (self-loop) --------------------------------
__global__ void k_deg_init(float* __restrict__ deg, int n) {
    int i = blockIdx.x * blockDim.x + threadIdx.x;
    if (i < n) deg[i] = 1.0f;
}

// ---- degree count: one thread per edge ------------------------------------
__global__ void k_deg_count(const int* __restrict__ dst, float* __restrict__ deg, int E) {
    int e = blockIdx.x * blockDim.x + threadIdx.x;
    if (e < E) unsafeAtomicAdd(&deg[dst[e]], 1.0f);
}

// ---- dis = rsqrt(deg), in place -------------------------------------------
__global__ void k_rsqrt(float* __restrict__ deg, int n) {
    int i = blockIdx.x * blockDim.x + threadIdx.x;
    if (i < n) deg[i] = rsqrtf(deg[i]);   // deg >= 1 always (self-loop)
}

// ---- GEMM1: h[N,16] = x[N,512] @ W[512,16] --------------------------------
// 256 threads = 16 rows/block, 16 threads per row (o = col). W1 in LDS (32KB).
__global__ __launch_bounds__(256) void k_gemm1(const float* __restrict__ x,
                                               const float* __restrict__ W,
                                               float* __restrict__ h, int nrows) {
    __shared__ float Ws[F_IN * F_OUT];            // 32 KB
    const float4* W4 = (const float4*)W;
    float4* Ws4 = (float4*)Ws;
    for (int i = threadIdx.x; i < (F_IN * F_OUT) / 4; i += 256) Ws4[i] = W4[i];
    __syncthreads();

    int r = blockIdx.x * 16 + (threadIdx.x >> 4);
    int o = threadIdx.x & 15;
    if (r >= nrows) return;

    const float4* xr = (const float4*)(x + (size_t)r * F_IN);
    float acc = 0.0f;
#pragma unroll 8
    for (int k4 = 0; k4 < F_IN / 4; ++k4) {
        float4 xv = xr[k4];                       // broadcast across 16 lanes
        int k = k4 * 4;
        acc = fmaf(xv.x, Ws[(k + 0) * 16 + o], acc);
        acc = fmaf(xv.y, Ws[(k + 1) * 16 + o], acc);
        acc = fmaf(xv.z, Ws[(k + 2) * 16 + o], acc);
        acc = fmaf(xv.w, Ws[(k + 3) * 16 + o], acc);
    }
    h[(size_t)r * 16 + o] = acc;
}

// ---- out[i,c] = dis[i]^2 * h[i,c]  (self-loop term == init, no memset) ----
__global__ void k_selfloop_init(const float* __restrict__ dis,
                                const float* __restrict__ h,
                                float* __restrict__ out, int total) {
    int t = blockIdx.x * blockDim.x + threadIdx.x;
    if (t >= total) return;
    int i = t >> 4;
    float d = dis[i];
    out[t] = d * d * h[t];
}

// ---- scatter: 16 threads per edge (one per column) ------------------------
__global__ __launch_bounds__(256) void k_scatter(const int* __restrict__ src,
                                                 const int* __restrict__ dst,
                                                 const float* __restrict__ dis,
                                                 const float* __restrict__ h,
                                                 float* __restrict__ out, int E) {
    int gid = blockIdx.x * 256 + threadIdx.x;
    int e = gid >> 4;
    if (e >= E) return;
    int c = gid & 15;
    int s = src[e];
    int d = dst[e];
    float norm = dis[s] * dis[d];
    float v = norm * h[(size_t)s * 16 + c];       // coalesced 64B gather per edge
    unsafeAtomicAdd(&out[(size_t)d * 16 + c], v); // hw global_atomic_add_f32
}

// ---- GEMM2 (16x16) fused with self-loop init of final out -----------------
// h2[N,16] = a[N,16] @ W2[16,16];  out[i,c] = dis[i]^2 * h2[i,c]
__global__ __launch_bounds__(256) void k_gemm2_fused(const float* __restrict__ a,
                                                     const float* __restrict__ W,
                                                     const float* __restrict__ dis,
                                                     float* __restrict__ h2,
                                                     float* __restrict__ out, int nrows) {
    __shared__ float Ws[F_OUT * F_OUT];           // 1 KB
    if (threadIdx.x < F_OUT * F_OUT) Ws[threadIdx.x] = W[threadIdx.x];
    __syncthreads();

    int r = blockIdx.x * 16 + (threadIdx.x >> 4);
    int o = threadIdx.x & 15;
    if (r >= nrows) return;

    const float* ar = a + (size_t)r * 16;
    float acc = 0.0f;
#pragma unroll
    for (int k = 0; k < 16; ++k) acc = fmaf(ar[k], Ws[k * 16 + o], acc);

    size_t idx = (size_t)r * 16 + o;
    h2[idx] = acc;
    float d = dis[r];
    out[idx] = d * d * acc;
}

extern "C" void kernel_launch(void* const* d_in, const int* in_sizes, int n_in,
                              void* d_out, int out_size, void* d_ws, size_t ws_size,
                              hipStream_t stream) {
    const float* x  = (const float*)d_in[0];
    const int*   ei = (const int*)d_in[1];        // [2, E] int32
    const float* W1 = (const float*)d_in[2];      // [512,16]
    const float* W2 = (const float*)d_in[3];      // [16,16]
    float* out = (float*)d_out;                   // [N,16]

    const int N = N_NODES;
    const int E = in_sizes[1] / 2;                // 3,200,000
    const int* src = ei;
    const int* dst = ei + E;

    // workspace layout (floats)
    float* ws   = (float*)d_ws;
    float* dis  = ws;                 // [N]      (deg, then rsqrt'd in place)
    float* h1   = dis + N;            // [N*16]
    float* out1 = h1 + (size_t)N * 16; // [N*16]
    float* h2   = out1 + (size_t)N * 16; // [N*16]

    const int B = 256;
    const int NC = N * F_OUT;         // 1.6M

    // degree (shared by both layers)
    k_deg_init<<<(N + B - 1) / B, B, 0, stream>>>(dis, N);
    k_deg_count<<<(E + B - 1) / B, B, 0, stream>>>(dst, dis, E);
    k_rsqrt<<<(N + B - 1) / B, B, 0, stream>>>(dis, N);

    // layer 1
    k_gemm1<<<(N + 15) / 16, B, 0, stream>>>(x, W1, h1, N);
    k_selfloop_init<<<(NC + B - 1) / B, B, 0, stream>>>(dis, h1, out1, NC);
    {
        long long threads = (long long)E * 16;
        k_scatter<<<(unsigned)((threads + B - 1) / B), B, 0, stream>>>(src, dst, dis, h1, out1, E);
    }

    // layer 2 (GEMM fused with self-loop init of final output)
    k_gemm2_fused<<<(N + 15) / 16, B, 0, stream>>>(out1, W2, dis, h2, out, N);
    {
        long long threads = (long long)E * 16;
        k_scatter<<<(unsigned)((threads + B - 1) / B), B, 0, stream>>>(src, dst, dis, h2, out, E);
    }
}